// Round 15
// baseline (85.499 us; speedup 1.0000x reference)
//
#include <hip/hip_runtime.h>
#include <hip/hip_bf16.h>

#define MAX_DET 300
#define NCAND 600           // MAX_DET * NUM_CLASSES
#define NPAD 640            // padded candidate stride
#define SCORE_THR 1e-3f
#define IOU_THR 0.7f
#define EPSF 1e-7f

typedef float float4u __attribute__((ext_vector_type(4), aligned(4)));

// ws layout (floats):
//   [0, 1024)        partial conv sums: (b*16+oc)*16 + chunk
//   [29200, 77200)   mask (u64), 4 x 600 x 10

static __device__ inline unsigned long long readlane64(unsigned long long v, int l) {
  unsigned int lo = (unsigned int)v;
  unsigned int hi = (unsigned int)(v >> 32);
  unsigned int slo = (unsigned int)__builtin_amdgcn_readlane((int)lo, l);
  unsigned int shi = (unsigned int)__builtin_amdgcn_readlane((int)hi, l);
  return ((unsigned long long)shi << 32) | (unsigned long long)slo;
}

// 1024 blocks: blk = (b*16 + oc)*16 + chunk. Each thread: one 4-px pooled strip.
__global__ __launch_bounds__(256) void k_conv_pool(
    const float* __restrict__ x, const float* __restrict__ cw,
    const float* __restrict__ cb, float* __restrict__ partial) {
  const int blk = blockIdx.x;
  const int chunk = blk & 15;
  const int oc = (blk >> 4) & 15;
  const int b = blk >> 8;
  const int tid = threadIdx.x;

  float w[27];
#pragma unroll
  for (int i = 0; i < 27; ++i) w[i] = cw[oc * 27 + i];
  const float bias = cb[oc];
  const float* xb = x + b * 3 * 65536;

  const int strip = chunk * 256 + tid;   // 0..4095
  const int py = strip >> 5;             // pooled row 0..127
  const int x0 = (strip & 31) * 4;       // pooled col start

  float cc0[4], cc1[4], cc2[4], cc3[4];
#pragma unroll
  for (int i = 0; i < 4; ++i) { cc0[i] = 0.f; cc1[i] = 0.f; cc2[i] = 0.f; cc3[i] = 0.f; }

#pragma unroll
  for (int ic = 0; ic < 3; ++ic) {
    const float* xc = xb + ic * 65536;
    const float* wc = w + ic * 9;
#pragma unroll
    for (int r = 0; r < 4; ++r) {
      const int y = 2 * py - 1 + r;
      if (y < 0 || y > 255) continue;
      const float* xr = xc + y * 256;
      float buf[12];
#pragma unroll
      for (int k = 0; k < 3; ++k) {
        const int c0 = 2 * x0 - 1 + 4 * k;
        if (c0 >= 0 && c0 + 3 <= 255) {
          const float4u v = *reinterpret_cast<const float4u*>(xr + c0);
          buf[4 * k + 0] = v.x; buf[4 * k + 1] = v.y;
          buf[4 * k + 2] = v.z; buf[4 * k + 3] = v.w;
        } else {
#pragma unroll
          for (int j = 0; j < 4; ++j) {
            const int c = c0 + j;
            buf[4 * k + j] = (c >= 0 && c <= 255) ? xr[c] : 0.f;
          }
        }
      }
#pragma unroll
      for (int i = 0; i < 4; ++i) {
        const float b0 = buf[2 * i], b1 = buf[2 * i + 1],
                    b2 = buf[2 * i + 2], b3 = buf[2 * i + 3];
        if (r <= 2) {
          const float w0 = wc[r * 3], w1 = wc[r * 3 + 1], w2 = wc[r * 3 + 2];
          cc0[i] += b0 * w0 + b1 * w1 + b2 * w2;
          cc1[i] += b1 * w0 + b2 * w1 + b3 * w2;
        }
        if (r >= 1) {
          const float w0 = wc[(r - 1) * 3], w1 = wc[(r - 1) * 3 + 1],
                      w2 = wc[(r - 1) * 3 + 2];
          cc2[i] += b0 * w0 + b1 * w1 + b2 * w2;
          cc3[i] += b1 * w0 + b2 * w1 + b3 * w2;
        }
      }
    }
  }

  float acc = 0.f;
#pragma unroll
  for (int i = 0; i < 4; ++i) {
    const float m = fmaxf(fmaxf(cc0[i], cc1[i]), fmaxf(cc2[i], cc3[i]));
    acc += fmaxf(m + bias, 0.f);
  }

  __shared__ float red[256];
  red[tid] = acc;
  __syncthreads();
  for (int s = 128; s > 0; s >>= 1) {
    if (tid < s) red[tid] += red[tid + s];
    __syncthreads();
  }
  if (tid == 0) partial[blk] = red[0];
}

// Shared local-prep: fmean + heads (explicit fmaf for cross-kernel bit
// identity) + ballot rank sort. 1024 threads. Fills sc, sbox, order.
static __device__ __forceinline__ void prep_local(
    int b, int tid, int wid, int lane,
    const float* __restrict__ partial,
    const float* __restrict__ bw, const float* __restrict__ bb,
    const float* __restrict__ cwm, const float* __restrict__ cbb,
    const float* __restrict__ aw, const float* __restrict__ ab,
    float* fm, float* red2, float* sc, float* sbox, int* order) {
  if (tid < 256) {
    const int oc = tid >> 4, j = tid & 15;
    red2[tid] = partial[(b * 16 + oc) * 16 + j];
  }
  for (int m = NCAND + tid; m < NPAD; m += 1024) sc[m] = -1e30f;
  __syncthreads();
  if (tid < 16) {
    float s = 0.f;
#pragma unroll
    for (int k = 0; k < 16; ++k) s += red2[tid * 16 + k];
    fm[tid] = s * (1.0f / 16384.0f);
  }
  __syncthreads();

  float f[16];
#pragma unroll
  for (int k = 0; k < 16; ++k) f[k] = fm[k];

  for (int o = tid; o < 4 * MAX_DET; o += 1024) {
    const float4u* wp = reinterpret_cast<const float4u*>(bw + o * 16);
    const float4u v0 = wp[0], v1 = wp[1], v2 = wp[2], v3 = wp[3];
    float wrow[16] = {v0.x, v0.y, v0.z, v0.w, v1.x, v1.y, v1.z, v1.w,
                      v2.x, v2.y, v2.z, v2.w, v3.x, v3.y, v3.z, v3.w};
    float acc = bb[o];
#pragma unroll
    for (int k = 0; k < 16; ++k) acc = fmaf(wrow[k], f[k], acc);
    const int d = o >> 2, j = o & 3;
    sbox[d * 5 + j] = acc;
  }
  if (tid < MAX_DET) {
    const int o = tid;
    const float4u* wp = reinterpret_cast<const float4u*>(aw + o * 16);
    const float4u v0 = wp[0], v1 = wp[1], v2 = wp[2], v3 = wp[3];
    float wrow[16] = {v0.x, v0.y, v0.z, v0.w, v1.x, v1.y, v1.z, v1.w,
                      v2.x, v2.y, v2.z, v2.w, v3.x, v3.y, v3.z, v3.w};
    float acc = ab[o];
#pragma unroll
    for (int k = 0; k < 16; ++k) acc = fmaf(wrow[k], f[k], acc);
    sbox[o * 5 + 4] = acc;
  }
  if (tid >= 512 && tid < 512 + MAX_DET) {
    const int p = tid - 512;
    const float4u* wp0 = reinterpret_cast<const float4u*>(cwm + (2 * p) * 16);
    const float4u* wp1 = reinterpret_cast<const float4u*>(cwm + (2 * p + 1) * 16);
    const float4u u0 = wp0[0], u1 = wp0[1], u2 = wp0[2], u3 = wp0[3];
    const float4u t0 = wp1[0], t1 = wp1[1], t2 = wp1[2], t3 = wp1[3];
    float w0r[16] = {u0.x, u0.y, u0.z, u0.w, u1.x, u1.y, u1.z, u1.w,
                     u2.x, u2.y, u2.z, u2.w, u3.x, u3.y, u3.z, u3.w};
    float w1r[16] = {t0.x, t0.y, t0.z, t0.w, t1.x, t1.y, t1.z, t1.w,
                     t2.x, t2.y, t2.z, t2.w, t3.x, t3.y, t3.z, t3.w};
    float a0 = cbb[2 * p], a1 = cbb[2 * p + 1];
#pragma unroll
    for (int k = 0; k < 16; ++k) {
      a0 = fmaf(w0r[k], f[k], a0);
      a1 = fmaf(w1r[k], f[k], a1);
    }
    const float mx = fmaxf(a0, a1);
    const float e0 = expf(a0 - mx), e1 = expf(a1 - mx);
    const float inv = 1.f / (e0 + e1);
    sc[p * 2 + 0] = e0 * inv;
    sc[p * 2 + 1] = e1 * inv;
  }
  __syncthreads();

  float sreg[10];
#pragma unroll
  for (int k = 0; k < 10; ++k) sreg[k] = sc[k * 64 + lane];

  for (int t = 0; t < 38; ++t) {
    const int i = t * 16 + wid;         // wave-uniform
    if (i < NCAND) {
      const float si = sc[i];           // LDS broadcast read
      int r = 0;
#pragma unroll
      for (int k = 0; k < 10; ++k) {
        const int j = k * 64 + lane;
        const bool c = (sreg[k] > si) || (sreg[k] == si && j < i);
        r += (int)__popcll(__ballot(c));
      }
      if (lane == 0) order[r] = i;
    }
  }
  __syncthreads();
}

// 152 blocks x 1024: blk = b*38 + rg. Local prep, sorted gaussian params in
// LDS, then each wave builds suppression row rg*16+wid via 10 ballots.
__global__ __launch_bounds__(1024) void k_mask(
    const float* __restrict__ partial,
    const float* __restrict__ bw, const float* __restrict__ bb,
    const float* __restrict__ cwm, const float* __restrict__ cbb,
    const float* __restrict__ aw, const float* __restrict__ ab,
    unsigned long long* __restrict__ mask) {
  const int blk = blockIdx.x;
  const int b = blk / 38, rg = blk % 38;
  const int tid = threadIdx.x;
  const int wid = tid >> 6, lane = tid & 63;

  __shared__ float fm[16];
  __shared__ float red2[256];
  __shared__ float sc[NPAD];
  __shared__ float sbox[MAX_DET * 5];
  __shared__ int order[NCAND];
  __shared__ float sx[NCAND], sy[NCAND], sA[NCAND], sB[NCAND], sC[NCAND],
      sD[NCAND];

  prep_local(b, tid, wid, lane, partial, bw, bb, cwm, cbb, aw, ab,
             fm, red2, sc, sbox, order);

  // sorted gaussian params into LDS
  if (tid < NCAND) {
    const int i = order[tid];
    const float* bp = sbox + (i >> 1) * 5;
    const float cx = bp[0], cy = bp[1], w = bp[2], h = bp[3], t = bp[4];
    const float ct = cosf(t), st = sinf(t);
    const float w2 = w * w * (1.f / 12.f), h2 = h * h * (1.f / 12.f);
    const float a = w2 * ct * ct + h2 * st * st;
    const float bb2 = w2 * st * st + h2 * ct * ct;
    const float c = (w2 - h2) * ct * st;
    sx[tid] = cx; sy[tid] = cy; sA[tid] = a; sB[tid] = bb2; sC[tid] = c;
    sD[tid] = fmaxf(a * bb2 - c * c, 0.f);
  }
  __syncthreads();

  const int i = rg * 16 + wid;   // sorted row
  if (i < NCAND) {
    const float x1 = sx[i], y1 = sy[i], a1 = sA[i], b1 = sB[i], c1 = sC[i],
                d1 = sD[i];
    const int li = order[i] & 1;
#pragma unroll
    for (int w = 0; w < 10; ++w) {
      const int j = w * 64 + lane;
      const int jc = j < NCAND ? j : NCAND - 1;
      const float x2 = sx[jc], y2 = sy[jc], a2 = sA[jc], b2 = sB[jc],
                  c2 = sC[jc], d2 = sD[jc];
      const float as = a1 + a2, bs = b1 + b2, cs = c1 + c2;
      const float dxx = x2 - x1, dyy = y1 - y2;
      const float denom = as * bs - cs * cs + EPSF;
      const float rden = 1.f / denom;
      const float t1v = 0.25f * (as * dyy * dyy + bs * dxx * dxx) * rden;
      const float t2v = 0.5f * (cs * dxx * dyy) * rden;
      const float t3v = 0.5f * logf(denom / (4.f * sqrtf(d1 * d2) + EPSF) + EPSF);
      float bd = t1v + t2v + t3v;
      bd = fminf(fmaxf(bd, EPSF), 100.f);
      const float hd = sqrtf(1.f - expf(-bd) + EPSF);
      const bool cond = (j > i) && (j < NCAND) && ((order[jc] & 1) == li) &&
                        ((1.f - hd) > IOU_THR);
      const unsigned long long mw = __ballot(cond);
      if (lane == 0) mask[(b * NCAND + i) * 10 + w] = mw;
    }
  }
}

// 4 blocks x 1024: mask->LDS copy (issued first, overlaps local prep), then
// scalar greedy scan over nonzero rows + output scatter.
__global__ __launch_bounds__(1024) void k_scan(
    const float* __restrict__ partial,
    const float* __restrict__ bw, const float* __restrict__ bb,
    const float* __restrict__ cwm, const float* __restrict__ cbb,
    const float* __restrict__ aw, const float* __restrict__ ab,
    const unsigned long long* __restrict__ mask, float* __restrict__ out) {
  const int b = blockIdx.x;
  const int tid = threadIdx.x;
  const int wid = tid >> 6, lane = tid & 63;

  __shared__ float fm[16];
  __shared__ float red2[256];
  __shared__ float sc[NPAD];
  __shared__ float sbox[MAX_DET * 5];
  __shared__ int order[NCAND];
  __shared__ unsigned long long m[NCAND * 10];
  __shared__ float ssc[NCAND];
  __shared__ unsigned long long keepw[10];
  __shared__ unsigned long long validbm[10];
  __shared__ unsigned long long nzbm[10];

  // mask copy first: independent of prep, overlaps its latency
  const unsigned long long* mg = mask + b * NCAND * 10;
  for (int k = tid; k < NCAND * 10; k += 1024) m[k] = mg[k];

  prep_local(b, tid, wid, lane, partial, bw, bb, cwm, cbb, aw, ab,
             fm, red2, sc, sbox, order);

  if (tid < NCAND) ssc[tid] = sc[order[tid]];
  __syncthreads();

  // ballot-built bitmaps: valid (score>thr) and nonzero-mask rows
  if (wid < 10) {
    const int r = wid * 64 + lane;
    bool valid = false;
    unsigned long long nzr = 0ULL;
    if (r < NCAND) {
      valid = ssc[r] > SCORE_THR;
      for (int k = 0; k < 10; ++k) nzr |= m[r * 10 + k];
    }
    const unsigned long long vb = __ballot(valid);
    const unsigned long long nb = __ballot(nzr != 0ULL);
    if (lane == 0) { validbm[wid] = vb; nzbm[wid] = nb; }
  }
  __syncthreads();

  // wave-0 scalar greedy scan
  if (tid < 64) {
    unsigned long long keep = (lane < 10) ? validbm[lane] : 0ULL;
    const unsigned long long nzv = (lane < 10) ? nzbm[lane] : 0ULL;
#pragma unroll
    for (int w = 0; w < 10; ++w) {
      unsigned long long nzs = readlane64(nzv, w);
      unsigned long long ks = readlane64(keep, w);
      while (nzs) {
        const int bit = __builtin_ctzll(nzs);
        nzs &= nzs - 1ULL;
        if ((ks >> bit) & 1ULL) {
          const int i = w * 64 + bit;
          unsigned long long row = 0ULL;
          if (lane < 10) row = m[i * 10 + lane];
          keep &= ~row;
          ks &= ~readlane64(row, w);
        }
      }
    }
    if (lane < 10) keepw[lane] = keep;
  }
  __syncthreads();

  for (int k = tid; k < MAX_DET * 5; k += 1024) out[b * MAX_DET * 5 + k] = 0.f;
  if (tid < MAX_DET) {
    out[6000 + b * MAX_DET + tid] = 0.f;   // scores
    out[7200 + b * MAX_DET + tid] = 0.f;   // labels
  }
  __syncthreads();

  if (tid < NCAND) {
    const int r = tid;
    const int w = r >> 6, bitp = r & 63;
    if ((keepw[w] >> bitp) & 1ULL) {
      int pos = 0;
      for (int ww = 0; ww < w; ++ww) pos += __popcll(keepw[ww]);
      pos += __popcll(keepw[w] & ((1ULL << bitp) - 1ULL));
      if (pos < MAX_DET) {
        const int i = order[r];
        const float* bp = sbox + (i >> 1) * 5;
        float* ob = out + (b * MAX_DET + pos) * 5;
        ob[0] = bp[0]; ob[1] = bp[1]; ob[2] = bp[2]; ob[3] = bp[3]; ob[4] = bp[4];
        out[6000 + b * MAX_DET + pos] = ssc[r];
        out[7200 + b * MAX_DET + pos] = (float)(i & 1);
      }
    }
  }
  if (tid == 0) {
    int total = 0;
    for (int ww = 0; ww < 10; ++ww) total += __popcll(keepw[ww]);
    if (total > MAX_DET) total = MAX_DET;
    out[8400 + b] = (float)total;
  }
}

extern "C" void kernel_launch(void* const* d_in, const int* in_sizes, int n_in,
                              void* d_out, int out_size, void* d_ws, size_t ws_size,
                              hipStream_t stream) {
  const float* x      = (const float*)d_in[0];
  const float* conv_w = (const float*)d_in[1];
  const float* conv_b = (const float*)d_in[2];
  const float* bbox_w = (const float*)d_in[3];
  const float* bbox_b = (const float*)d_in[4];
  const float* cls_w  = (const float*)d_in[5];
  const float* cls_b  = (const float*)d_in[6];
  const float* ang_w  = (const float*)d_in[7];
  const float* ang_b  = (const float*)d_in[8];
  float* out = (float*)d_out;
  float* ws = (float*)d_ws;

  float* partial = ws;            // 1024: (b*16+oc)*16+chunk
  unsigned long long* mask = (unsigned long long*)(ws + 29200);  // 4*600*10 u64

  k_conv_pool<<<1024, 256, 0, stream>>>(x, conv_w, conv_b, partial);
  k_mask<<<152, 1024, 0, stream>>>(partial, bbox_w, bbox_b, cls_w, cls_b,
                                   ang_w, ang_b, mask);
  k_scan<<<4, 1024, 0, stream>>>(partial, bbox_w, bbox_b, cls_w, cls_b,
                                 ang_w, ang_b, mask, out);
}

// Round 16
// 57.760 us; speedup vs baseline: 1.4802x; 1.4802x over previous
//
#include <hip/hip_runtime.h>
#include <hip/hip_bf16.h>

#define MAX_DET 300
#define NCAND 600           // MAX_DET * NUM_CLASSES
#define NPAD 640            // padded candidate stride
#define SCORE_THR 1e-3f
#define IOU_THR 0.7f
#define EPSF 1e-7f

typedef float float4u __attribute__((ext_vector_type(4), aligned(4)));

// ws layout (floats):
//   [0, 1024)        partial conv sums: (b*16+oc)*16 + chunk
//   [1024, 7024)     boxes5 (4*300*5)
//   [8720, 26640)    sorted params: 4 batches x 7 arrays x 640  (x,y,A,B,C,D,s)
//   [26640, 29200)   order (int), 4 x 640
//   [29200, 77200)   mask (u64), 4 x 600 x 10

static __device__ inline unsigned long long readlane64(unsigned long long v, int l) {
  unsigned int lo = (unsigned int)v;
  unsigned int hi = (unsigned int)(v >> 32);
  unsigned int slo = (unsigned int)__builtin_amdgcn_readlane((int)lo, l);
  unsigned int shi = (unsigned int)__builtin_amdgcn_readlane((int)hi, l);
  return ((unsigned long long)shi << 32) | (unsigned long long)slo;
}

// 1024 blocks: blk = (b*16 + oc)*16 + chunk. Each thread: one 4-px pooled strip.
__global__ __launch_bounds__(256) void k_conv_pool(
    const float* __restrict__ x, const float* __restrict__ cw,
    const float* __restrict__ cb, float* __restrict__ partial) {
  const int blk = blockIdx.x;
  const int chunk = blk & 15;
  const int oc = (blk >> 4) & 15;
  const int b = blk >> 8;
  const int tid = threadIdx.x;

  float w[27];
#pragma unroll
  for (int i = 0; i < 27; ++i) w[i] = cw[oc * 27 + i];
  const float bias = cb[oc];
  const float* xb = x + b * 3 * 65536;

  const int strip = chunk * 256 + tid;   // 0..4095
  const int py = strip >> 5;             // pooled row 0..127
  const int x0 = (strip & 31) * 4;       // pooled col start: 0,4,...,124

  float cc0[4], cc1[4], cc2[4], cc3[4];
#pragma unroll
  for (int i = 0; i < 4; ++i) { cc0[i] = 0.f; cc1[i] = 0.f; cc2[i] = 0.f; cc3[i] = 0.f; }

#pragma unroll
  for (int ic = 0; ic < 3; ++ic) {
    const float* xc = xb + ic * 65536;
    const float* wc = w + ic * 9;
#pragma unroll
    for (int r = 0; r < 4; ++r) {
      const int y = 2 * py - 1 + r;
      if (y < 0 || y > 255) continue;
      const float* xr = xc + y * 256;
      float buf[12];
#pragma unroll
      for (int k = 0; k < 3; ++k) {
        const int c0 = 2 * x0 - 1 + 4 * k;
        if (c0 >= 0 && c0 + 3 <= 255) {
          const float4u v = *reinterpret_cast<const float4u*>(xr + c0);
          buf[4 * k + 0] = v.x; buf[4 * k + 1] = v.y;
          buf[4 * k + 2] = v.z; buf[4 * k + 3] = v.w;
        } else {
#pragma unroll
          for (int j = 0; j < 4; ++j) {
            const int c = c0 + j;
            buf[4 * k + j] = (c >= 0 && c <= 255) ? xr[c] : 0.f;
          }
        }
      }
#pragma unroll
      for (int i = 0; i < 4; ++i) {
        const float b0 = buf[2 * i], b1 = buf[2 * i + 1],
                    b2 = buf[2 * i + 2], b3 = buf[2 * i + 3];
        if (r <= 2) {
          const float w0 = wc[r * 3], w1 = wc[r * 3 + 1], w2 = wc[r * 3 + 2];
          cc0[i] += b0 * w0 + b1 * w1 + b2 * w2;
          cc1[i] += b1 * w0 + b2 * w1 + b3 * w2;
        }
        if (r >= 1) {
          const float w0 = wc[(r - 1) * 3], w1 = wc[(r - 1) * 3 + 1],
                      w2 = wc[(r - 1) * 3 + 2];
          cc2[i] += b0 * w0 + b1 * w1 + b2 * w2;
          cc3[i] += b1 * w0 + b2 * w1 + b3 * w2;
        }
      }
    }
  }

  float acc = 0.f;
#pragma unroll
  for (int i = 0; i < 4; ++i) {
    const float m = fmaxf(fmaxf(cc0[i], cc1[i]), fmaxf(cc2[i], cc3[i]));
    acc += fmaxf(m + bias, 0.f);
  }

  __shared__ float red[256];
  red[tid] = acc;
  __syncthreads();
  for (int s = 128; s > 0; s >>= 1) {
    if (tid < s) red[tid] += red[tid + s];
    __syncthreads();
  }
  if (tid == 0) partial[blk] = red[0];
}

// Fused heads + ballot rank sort + sorted gaussian params.
// One block per batch, 1024 threads (16 waves).
__global__ __launch_bounds__(1024) void k_prep(
    const float* __restrict__ partial,
    const float* __restrict__ bw, const float* __restrict__ bb,
    const float* __restrict__ cwm, const float* __restrict__ cbb,
    const float* __restrict__ aw, const float* __restrict__ ab,
    float* __restrict__ boxes5, float* __restrict__ sparams,
    int* __restrict__ order_g) {
  const int b = blockIdx.x;
  const int tid = threadIdx.x;
  const int wid = tid >> 6, lane = tid & 63;

  __shared__ float fm[16];
  __shared__ float red2[256];
  __shared__ float sc[NPAD];
  __shared__ float sbox[MAX_DET * 5];
  __shared__ int order[NCAND];

  if (tid < 256) {
    const int oc = tid >> 4, j = tid & 15;
    red2[tid] = partial[(b * 16 + oc) * 16 + j];
  }
  for (int m = NCAND + tid; m < NPAD; m += 1024) sc[m] = -1e30f;
  __syncthreads();
  if (tid < 16) {
    float s = 0.f;
#pragma unroll
    for (int k = 0; k < 16; ++k) s += red2[tid * 16 + k];
    fm[tid] = s * (1.0f / 16384.0f);
  }
  __syncthreads();

  float f[16];
#pragma unroll
  for (int k = 0; k < 16; ++k) f[k] = fm[k];

  // --- bbox rows (1200), coalesced float4 row loads ---
  for (int o = tid; o < 4 * MAX_DET; o += 1024) {
    const float4u* wp = reinterpret_cast<const float4u*>(bw + o * 16);
    const float4u v0 = wp[0], v1 = wp[1], v2 = wp[2], v3 = wp[3];
    float wrow[16] = {v0.x, v0.y, v0.z, v0.w, v1.x, v1.y, v1.z, v1.w,
                      v2.x, v2.y, v2.z, v2.w, v3.x, v3.y, v3.z, v3.w};
    float acc = bb[o];
#pragma unroll
    for (int k = 0; k < 16; ++k) acc += wrow[k] * f[k];
    const int d = o >> 2, j = o & 3;
    sbox[d * 5 + j] = acc;
    boxes5[(b * MAX_DET + d) * 5 + j] = acc;
  }
  // --- angle rows (300) ---
  if (tid < MAX_DET) {
    const int o = tid;
    const float4u* wp = reinterpret_cast<const float4u*>(aw + o * 16);
    const float4u v0 = wp[0], v1 = wp[1], v2 = wp[2], v3 = wp[3];
    float wrow[16] = {v0.x, v0.y, v0.z, v0.w, v1.x, v1.y, v1.z, v1.w,
                      v2.x, v2.y, v2.z, v2.w, v3.x, v3.y, v3.z, v3.w};
    float acc = ab[o];
#pragma unroll
    for (int k = 0; k < 16; ++k) acc += wrow[k] * f[k];
    sbox[o * 5 + 4] = acc;
    boxes5[(b * MAX_DET + o) * 5 + 4] = acc;
  }
  // --- cls pairs (300) + softmax ---
  if (tid >= 512 && tid < 512 + MAX_DET) {
    const int p = tid - 512;
    const float4u* wp0 = reinterpret_cast<const float4u*>(cwm + (2 * p) * 16);
    const float4u* wp1 = reinterpret_cast<const float4u*>(cwm + (2 * p + 1) * 16);
    const float4u u0 = wp0[0], u1 = wp0[1], u2 = wp0[2], u3 = wp0[3];
    const float4u t0 = wp1[0], t1 = wp1[1], t2 = wp1[2], t3 = wp1[3];
    float w0r[16] = {u0.x, u0.y, u0.z, u0.w, u1.x, u1.y, u1.z, u1.w,
                     u2.x, u2.y, u2.z, u2.w, u3.x, u3.y, u3.z, u3.w};
    float w1r[16] = {t0.x, t0.y, t0.z, t0.w, t1.x, t1.y, t1.z, t1.w,
                     t2.x, t2.y, t2.z, t2.w, t3.x, t3.y, t3.z, t3.w};
    float a0 = cbb[2 * p], a1 = cbb[2 * p + 1];
#pragma unroll
    for (int k = 0; k < 16; ++k) {
      a0 += w0r[k] * f[k];
      a1 += w1r[k] * f[k];
    }
    const float mx = fmaxf(a0, a1);
    const float e0 = expf(a0 - mx), e1 = expf(a1 - mx);
    const float inv = 1.f / (e0 + e1);
    sc[p * 2 + 0] = e0 * inv;
    sc[p * 2 + 1] = e1 * inv;
  }
  __syncthreads();

  // --- rank sort: register scores + LDS-broadcast pivot, ballot-popcount ---
  float sreg[10];
#pragma unroll
  for (int k = 0; k < 10; ++k) sreg[k] = sc[k * 64 + lane];

  for (int t = 0; t < 38; ++t) {
    const int i = t * 16 + wid;         // wave-uniform
    if (i < NCAND) {
      const float si = sc[i];           // LDS broadcast read
      int r = 0;
#pragma unroll
      for (int k = 0; k < 10; ++k) {
        const int j = k * 64 + lane;
        const bool c = (sreg[k] > si) || (sreg[k] == si && j < i);
        r += (int)__popcll(__ballot(c));
      }
      if (lane == 0) order[r] = i;
    }
  }
  __syncthreads();

  // --- sorted gaussian params ---
  float* P = sparams + b * 7 * NPAD;
  if (tid < NCAND) {
    const int r = tid;
    const int i = order[r];
    order_g[b * NPAD + r] = i;
    const float* bp = sbox + (i >> 1) * 5;
    const float cx = bp[0], cy = bp[1], w = bp[2], h = bp[3], t = bp[4];
    const float ct = cosf(t), st = sinf(t);
    const float w2 = w * w * (1.f / 12.f), h2 = h * h * (1.f / 12.f);
    const float a = w2 * ct * ct + h2 * st * st;
    const float bb2 = w2 * st * st + h2 * ct * ct;
    const float c = (w2 - h2) * ct * st;
    P[0 * NPAD + r] = cx;
    P[1 * NPAD + r] = cy;
    P[2 * NPAD + r] = a;
    P[3 * NPAD + r] = bb2;
    P[4 * NPAD + r] = c;
    P[5 * NPAD + r] = fmaxf(a * bb2 - c * c, 0.f);
    P[6 * NPAD + r] = sc[i];
  }
}

// One wave per sorted row; 10 ballots build the 600-bit suppression row.
__global__ __launch_bounds__(256) void k_mask(
    const float* __restrict__ sparams, const int* __restrict__ order_g,
    unsigned long long* __restrict__ mask) {
  const int wid = threadIdx.x >> 6, lane = threadIdx.x & 63;
  const int g = blockIdx.x * 4 + wid;  // 0 .. 2399
  const int b = g / NCAND, i = g % NCAND;

  const float* P = sparams + b * 7 * NPAD;
  const int* og = order_g + b * NPAD;
  const float x1 = P[i], y1 = P[NPAD + i], a1 = P[2 * NPAD + i],
              b1 = P[3 * NPAD + i], c1 = P[4 * NPAD + i], d1 = P[5 * NPAD + i];
  const int li = og[i] & 1;

#pragma unroll
  for (int w = 0; w < 10; ++w) {
    const int j = w * 64 + lane;
    const int jc = j < NCAND ? j : NCAND - 1;
    const float x2 = P[jc], y2 = P[NPAD + jc], a2 = P[2 * NPAD + jc],
                b2 = P[3 * NPAD + jc], c2 = P[4 * NPAD + jc],
                d2 = P[5 * NPAD + jc];
    const float as = a1 + a2, bs = b1 + b2, cs = c1 + c2;
    const float dxx = x2 - x1, dyy = y1 - y2;
    const float denom = as * bs - cs * cs + EPSF;
    const float rden = 1.f / denom;
    const float t1v = 0.25f * (as * dyy * dyy + bs * dxx * dxx) * rden;
    const float t2v = 0.5f * (cs * dxx * dyy) * rden;
    const float t3v = 0.5f * logf(denom / (4.f * sqrtf(d1 * d2) + EPSF) + EPSF);
    float bd = t1v + t2v + t3v;
    bd = fminf(fmaxf(bd, EPSF), 100.f);
    const float hd = sqrtf(1.f - expf(-bd) + EPSF);
    const bool cond = (j > i) && (j < NCAND) && ((og[jc] & 1) == li) &&
                      ((1.f - hd) > IOU_THR);
    const unsigned long long mw = __ballot(cond);
    if (lane == 0) mask[(b * NCAND + i) * 10 + w] = mw;
  }
}

// Scalar greedy scan over nonzero-mask rows only + output scatter. 1024 threads.
__global__ __launch_bounds__(1024) void k_scan(
    const float* __restrict__ boxes5, const float* __restrict__ sparams,
    const int* __restrict__ order_g, const unsigned long long* __restrict__ mask,
    float* __restrict__ out) {
  const int b = blockIdx.x;
  const int tid = threadIdx.x;
  const int wid = tid >> 6, lane = tid & 63;

  __shared__ unsigned long long m[NCAND * 10];
  __shared__ float ssc[NCAND];
  __shared__ unsigned long long keepw[10];
  __shared__ unsigned long long validbm[10];
  __shared__ unsigned long long nzbm[10];

  // coalesced global -> LDS mask copy (1024 threads, 16 waves in flight)
  const unsigned long long* mg = mask + b * NCAND * 10;
  for (int k = tid; k < NCAND * 10; k += 1024) m[k] = mg[k];
  const float* P = sparams + b * 7 * NPAD;
  if (tid < NCAND) ssc[tid] = P[6 * NPAD + tid];
  __syncthreads();

  // ballot-built bitmaps: valid (score>thr) and nonzero-mask rows
  if (wid < 10) {
    const int r = wid * 64 + lane;
    bool valid = false;
    unsigned long long nzr = 0ULL;
    if (r < NCAND) {
      valid = ssc[r] > SCORE_THR;
      for (int k = 0; k < 10; ++k) nzr |= m[r * 10 + k];
    }
    const unsigned long long vb = __ballot(valid);
    const unsigned long long nb = __ballot(nzr != 0ULL);
    if (lane == 0) { validbm[wid] = vb; nzbm[wid] = nb; }
  }
  __syncthreads();

  // wave-0 scalar greedy scan: visit only rows with nonzero suppression mask
  if (tid < 64) {
    unsigned long long keep = (lane < 10) ? validbm[lane] : 0ULL;
    const unsigned long long nzv = (lane < 10) ? nzbm[lane] : 0ULL;
#pragma unroll
    for (int w = 0; w < 10; ++w) {
      unsigned long long nzs = readlane64(nzv, w);
      unsigned long long ks = readlane64(keep, w);  // scalar cache of keep word w
      while (nzs) {
        const int bit = __builtin_ctzll(nzs);
        nzs &= nzs - 1ULL;
        if ((ks >> bit) & 1ULL) {
          const int i = w * 64 + bit;
          unsigned long long row = 0ULL;
          if (lane < 10) row = m[i * 10 + lane];
          keep &= ~row;
          ks &= ~readlane64(row, w);
        }
      }
    }
    if (lane < 10) keepw[lane] = keep;
  }
  __syncthreads();

  for (int k = tid; k < MAX_DET * 5; k += 1024) out[b * MAX_DET * 5 + k] = 0.f;
  if (tid < MAX_DET) {
    out[6000 + b * MAX_DET + tid] = 0.f;   // scores
    out[7200 + b * MAX_DET + tid] = 0.f;   // labels
  }
  __syncthreads();

  const int* og = order_g + b * NPAD;
  if (tid < NCAND) {
    const int r = tid;
    const int w = r >> 6, bitp = r & 63;
    if ((keepw[w] >> bitp) & 1ULL) {
      int pos = 0;
      for (int ww = 0; ww < w; ++ww) pos += __popcll(keepw[ww]);
      pos += __popcll(keepw[w] & ((1ULL << bitp) - 1ULL));
      if (pos < MAX_DET) {
        const int i = og[r];
        const float* bp = boxes5 + (b * MAX_DET + (i >> 1)) * 5;
        float* ob = out + (b * MAX_DET + pos) * 5;
        ob[0] = bp[0]; ob[1] = bp[1]; ob[2] = bp[2]; ob[3] = bp[3]; ob[4] = bp[4];
        out[6000 + b * MAX_DET + pos] = ssc[r];
        out[7200 + b * MAX_DET + pos] = (float)(i & 1);
      }
    }
  }
  if (tid == 0) {
    int total = 0;
    for (int ww = 0; ww < 10; ++ww) total += __popcll(keepw[ww]);
    if (total > MAX_DET) total = MAX_DET;
    out[8400 + b] = (float)total;
  }
}

extern "C" void kernel_launch(void* const* d_in, const int* in_sizes, int n_in,
                              void* d_out, int out_size, void* d_ws, size_t ws_size,
                              hipStream_t stream) {
  const float* x      = (const float*)d_in[0];
  const float* conv_w = (const float*)d_in[1];
  const float* conv_b = (const float*)d_in[2];
  const float* bbox_w = (const float*)d_in[3];
  const float* bbox_b = (const float*)d_in[4];
  const float* cls_w  = (const float*)d_in[5];
  const float* cls_b  = (const float*)d_in[6];
  const float* ang_w  = (const float*)d_in[7];
  const float* ang_b  = (const float*)d_in[8];
  float* out = (float*)d_out;
  float* ws = (float*)d_ws;

  float* partial = ws;            // 1024: (b*16+oc)*16+chunk
  float* boxes5  = ws + 1024;     // 6000
  float* sparams = ws + 8720;     // 4*7*640 = 17920
  int*   order_g = (int*)(ws + 26640);                       // 4*640
  unsigned long long* mask = (unsigned long long*)(ws + 29200);  // 4*600*10 u64

  k_conv_pool<<<1024, 256, 0, stream>>>(x, conv_w, conv_b, partial);
  k_prep<<<4, 1024, 0, stream>>>(partial, bbox_w, bbox_b, cls_w, cls_b,
                                 ang_w, ang_b, boxes5, sparams, order_g);
  k_mask<<<600, 256, 0, stream>>>(sparams, order_g, mask);
  k_scan<<<4, 1024, 0, stream>>>(boxes5, sparams, order_g, mask, out);
}